// Round 10
// baseline (122.087 us; speedup 1.0000x reference)
//
#include <hip/hip_runtime.h>
#include <hip/hip_bf16.h>
#include <math.h>

typedef short short8 __attribute__((ext_vector_type(8)));
typedef float f32x4 __attribute__((ext_vector_type(4)));

static constexpr int N = 8192;
static constexpr int FIN = 512;
static constexpr int FOUT = 128;
static constexpr int NJC = 16;      // j-chunks (BJ = N/NJC = 512) -> whbt slice fits LDS
static constexpr float PHI = 3.1415926f * 0.3f;
static constexpr float A_PARA = 0.5f;
static constexpr float EPS_BALL = 4e-3f;
static constexpr float L2E = 1.4426950408889634f;   // log2(e)

__device__ __forceinline__ unsigned short f2b(float f) {
    union { float f; unsigned u; } v; v.f = f;
    unsigned r = v.u + 0x7fffu + ((v.u >> 16) & 1u);
    return (unsigned short)(r >> 16);
}

// RN bf16 via HIP intrinsic (compiler can pair into v_cvt_pk_bf16_f32)
__device__ __forceinline__ short f2bn(float f) {
    __hip_bfloat16 h = __float2bfloat16(f);
    return *reinterpret_cast<short*>(&h);
}

// monotone f32 -> u32 key for atomicMax-based float max
__device__ __forceinline__ unsigned f2key(float x) {
    unsigned b = __float_as_uint(x);
    return (b & 0x80000000u) ? ~b : (b | 0x80000000u);
}
__device__ __forceinline__ float key2f(unsigned k) {
    unsigned b = (k & 0x80000000u) ? (k ^ 0x80000000u) : ~k;
    return __uint_as_float(b);
}

__device__ __forceinline__ short8 cvt8(float4 x0, float4 x1) {
    short8 r;
    r[0] = (short)f2b(x0.x); r[1] = (short)f2b(x0.y);
    r[2] = (short)f2b(x0.z); r[3] = (short)f2b(x0.w);
    r[4] = (short)f2b(x1.x); r[5] = (short)f2b(x1.y);
    r[6] = (short)f2b(x1.z); r[7] = (short)f2b(x1.w);
    return r;
}

// w = exp2( lrelu(s'+t') - m' ) masked by adj; everything pre-scaled by log2e.
__device__ __forceinline__ void cw(float* w, const int4 a, const float4 tv,
                                   float sA, float mA) {
    float z;
    z = sA + tv.x; w[0] = a.x > 0 ? __builtin_amdgcn_exp2f(fmaxf(z, 0.2f * z) - mA) : 0.f;
    z = sA + tv.y; w[1] = a.y > 0 ? __builtin_amdgcn_exp2f(fmaxf(z, 0.2f * z) - mA) : 0.f;
    z = sA + tv.z; w[2] = a.z > 0 ? __builtin_amdgcn_exp2f(fmaxf(z, 0.2f * z) - mA) : 0.f;
    z = sA + tv.w; w[3] = a.w > 0 ? __builtin_amdgcn_exp2f(fmaxf(z, 0.2f * z) - mA) : 0.f;
}

// Kernel 0: W f32[512][128] -> Wt bf16[128][512]; block 0 also zeroes Tkey + denb.
__global__ __launch_bounds__(256) void k0_wt(const float* __restrict__ W,
                                             unsigned short* __restrict__ Wt,
                                             unsigned* __restrict__ Tkey,
                                             float* __restrict__ denb) {
    __shared__ float sh[32][33];
    const int t = threadIdx.x;
    const int k0 = (blockIdx.x >> 2) * 32, c0 = (blockIdx.x & 3) * 32;
    {
        int r = t >> 3, c4 = (t & 7) * 4;
        float4 v = *(const float4*)(W + (size_t)(k0 + r) * FOUT + c0 + c4);
        sh[r][c4] = v.x; sh[r][c4 + 1] = v.y; sh[r][c4 + 2] = v.z; sh[r][c4 + 3] = v.w;
    }
    __syncthreads();
    int cc = t >> 3, k4 = (t & 7) * 4;
    ushort4 o;
    o.x = f2b(sh[k4][cc]); o.y = f2b(sh[k4 + 1][cc]);
    o.z = f2b(sh[k4 + 2][cc]); o.w = f2b(sh[k4 + 3][cc]);
    *(ushort4*)(Wt + (size_t)(c0 + cc) * FIN + k0 + k4) = o;
    if (blockIdx.x == 0) {
        if (t == 0) Tkey[0] = 0u;
        for (int i = t; i < N; i += 256) denb[i] = 0.f;
    }
}

// Kernel 1 (round-9 proven): Wh = h @ W via bf16 MFMA, full Wt staged in LDS.
__global__ __launch_bounds__(256) void k1_gemm(
    const float* __restrict__ h, const unsigned short* __restrict__ Wt,
    const float* __restrict__ a, unsigned short* __restrict__ whbt,
    float* __restrict__ s_out, float* __restrict__ t_out,
    unsigned* __restrict__ Tkey)
{
    __shared__ unsigned short wlds[128][520];   // 133 KB
    __shared__ unsigned short hsb[2][32][72];
    __shared__ float sred[32][2], tred[32][2];
    const int t = threadIdx.x, lane = t & 63, wave = t >> 6;
    const int i0 = blockIdx.x * 32;
    const int wr = wave & 1, wc = wave >> 1;
    const int arow = lane & 15, g = lane >> 4;
    const int sr = t >> 3, sc = (t & 7) * 8;
    const float* hp = h + (size_t)(i0 + sr) * FIN + sc;

    for (int idx = t; idx < (FOUT * FIN) / 8; idx += 256) {
        const int row = idx >> 6, col = (idx & 63) * 8;
        *(short8*)&wlds[row][col] = *(const short8*)(Wt + (size_t)row * FIN + col);
    }
    float4 x0 = *(const float4*)hp, x1 = *(const float4*)(hp + 4);
    *(short8*)&hsb[0][sr][sc] = cvt8(x0, x1);
    __syncthreads();

    f32x4 acc[4];
    const f32x4 zz = {0.f, 0.f, 0.f, 0.f};
    #pragma unroll
    for (int cf = 0; cf < 4; ++cf) acc[cf] = zz;

    #pragma unroll 1
    for (int kt = 0; kt < 8; ++kt) {
        const int cur = kt & 1;
        float4 y0, y1;
        if (kt < 7) {
            y0 = *(const float4*)(hp + (kt + 1) * 64);
            y1 = *(const float4*)(hp + (kt + 1) * 64 + 4);
        }
        #pragma unroll
        for (int js = 0; js < 64; js += 32) {
            short8 af = *(const short8*)&hsb[cur][wr * 16 + arow][js + g * 8];
            #pragma unroll
            for (int cf = 0; cf < 4; ++cf) {
                short8 bf = *(const short8*)&wlds[wc * 64 + cf * 16 + arow][kt * 64 + js + g * 8];
                acc[cf] = __builtin_amdgcn_mfma_f32_16x16x32_bf16(af, bf, acc[cf], 0, 0, 0);
            }
        }
        if (kt < 7) {
            *(short8*)&hsb[cur ^ 1][sr][sc] = cvt8(y0, y1);
            __syncthreads();
        }
    }

    float a1v[4], a2v[4];
    #pragma unroll
    for (int cf = 0; cf < 4; ++cf) {
        int col = wc * 64 + cf * 16 + arow;
        a1v[cf] = a[col]; a2v[cf] = a[FOUT + col];
    }
    #pragma unroll
    for (int cf = 0; cf < 4; ++cf) {
        int col = wc * 64 + cf * 16 + arow;
        ushort4 o;
        o.x = f2b(acc[cf][0]); o.y = f2b(acc[cf][1]);
        o.z = f2b(acc[cf][2]); o.w = f2b(acc[cf][3]);
        *(ushort4*)(whbt + (size_t)col * N + i0 + wr * 16 + g * 4) = o;
    }
    #pragma unroll
    for (int q = 0; q < 4; ++q) {
        float sp = acc[0][q]*a1v[0] + acc[1][q]*a1v[1] + acc[2][q]*a1v[2] + acc[3][q]*a1v[3];
        float tp = acc[0][q]*a2v[0] + acc[1][q]*a2v[1] + acc[2][q]*a2v[2] + acc[3][q]*a2v[3];
        #pragma unroll
        for (int m = 1; m < 16; m <<= 1) {
            sp += __shfl_xor(sp, m, 16);
            tp += __shfl_xor(tp, m, 16);
        }
        if (arow == 0) {
            sred[wr * 16 + g * 4 + q][wc] = sp;
            tred[wr * 16 + g * 4 + q][wc] = tp;
        }
    }
    __syncthreads();
    if (t < 32) {
        float sp = (sred[t][0] + sred[t][1]) * L2E;
        float tp = (tred[t][0] + tred[t][1]) * L2E;
        s_out[i0 + t] = sp;
        t_out[i0 + t] = tp;
        float m = tp;
        #pragma unroll
        for (int d = 1; d < 32; d <<= 1) m = fmaxf(m, __shfl_xor(m, d, 32));
        if (t == 0) atomicMax(Tkey, f2key(m));
    }
}

// Kernel 3: fused masked-softmax attention + PV (bf16 MFMA), BARRIER-FREE main loop.
// Grid 1024 = 64 i-tiles (BM=128) x 16 j-chunks (BJ=512), jc = blockIdx&15
// (XCD gets jc pairs {x, x+8}: 2x128 KB whbt slices, L2-resident).
// The whole whbt slice [128][512] (128 KB -> 133 KB padded) is staged to LDS
// ONCE; the 8-iteration main loop has NO __syncthreads, NO LDS writes, NO
// whbt loads — each wave free-runs: adj 2-deep register pipeline (2-slot,
// explicit 2x unroll: no runtime-indexed reg arrays), exp/pack, MFMA from
// static LDS. Row stride 1040 B -> 4-bank rotate -> 2-way alias (free, m136).
__global__ __launch_bounds__(512, 2) void k3_attn(
    const int* __restrict__ adj, const unsigned short* __restrict__ whbt,
    const float* __restrict__ s_in, const float* __restrict__ t_in,
    const unsigned* __restrict__ Tkey,
    unsigned short* __restrict__ num_bf, float* __restrict__ num_f32,
    float* __restrict__ den_out, int slice_mode)
{
    __shared__ unsigned short bt[128][520];   // 133 KB, whole whbt slice
    __shared__ float tl[512];
    const int t = threadIdx.x, lane = t & 63, wave = t >> 6;
    const int jc = blockIdx.x & (NJC - 1), it = blockIdx.x / NJC;
    const int i0 = it * 128, jbase = jc * (N / NJC);

    // stage whbt slice [128 FOUT][512 j] -> LDS (coalesced short8 chunks)
    for (int idx = t; idx < (128 * 512) / 8; idx += 512) {
        const int row = idx >> 6, col = (idx & 63) * 8;
        *(short8*)&bt[row][col] = *(const short8*)(whbt + (size_t)row * N + jbase + col);
    }
    tl[t] = t_in[jbase + t];

    const int arow = lane & 15, g = lane >> 4;
    const int grow = i0 + wave * 16 + arow;
    const float sA = s_in[grow];
    const float Tv = key2f(Tkey[0]);
    const float zT = sA + Tv;
    const float mA = fmaxf(zT, 0.2f * zT);
    const int* adjrow = adj + (size_t)grow * N;

    f32x4 acc[8];
    const f32x4 zz = {0.f, 0.f, 0.f, 0.f};
    #pragma unroll
    for (int c = 0; c < 8; ++c) acc[c] = zz;
    float den = 0.f;

    // adj 2-slot register pipeline: A <- jt0, B <- jt1
    int4 aA0 = *(const int4*)(adjrow + jbase + g * 8);
    int4 aA1 = *(const int4*)(adjrow + jbase + g * 8 + 4);
    int4 aA2 = *(const int4*)(adjrow + jbase + 32 + g * 8);
    int4 aA3 = *(const int4*)(adjrow + jbase + 32 + g * 8 + 4);
    int4 aB0 = *(const int4*)(adjrow + jbase + 64 + g * 8);
    int4 aB1 = *(const int4*)(adjrow + jbase + 64 + g * 8 + 4);
    int4 aB2 = *(const int4*)(adjrow + jbase + 96 + g * 8);
    int4 aB3 = *(const int4*)(adjrow + jbase + 96 + g * 8 + 4);

    __syncthreads();   // the ONLY barrier: staging complete

    // one iteration: uses slot U (current jt), refills U with jt+2 (issued first,
    // max latency cover; clamped redundant loads at the tail are never consumed)
#define K3_ITER(JT, U0, U1, U2, U3)                                            \
    {                                                                          \
        const int jl = (JT) * 64;                                              \
        const int jn = ((JT) + 2 < 8) ? (JT) + 2 : 7;                          \
        const int* ap = adjrow + jbase + jn * 64;                              \
        int4 f0 = *(const int4*)(ap + g * 8);                                  \
        int4 f1 = *(const int4*)(ap + g * 8 + 4);                              \
        int4 f2 = *(const int4*)(ap + 32 + g * 8);                             \
        int4 f3 = *(const int4*)(ap + 32 + g * 8 + 4);                         \
        float4 ta = *(const float4*)&tl[jl + g * 8];                           \
        float4 tb = *(const float4*)&tl[jl + g * 8 + 4];                       \
        float4 tc = *(const float4*)&tl[jl + 32 + g * 8];                      \
        float4 td = *(const float4*)&tl[jl + 32 + g * 8 + 4];                  \
        float w[16];                                                           \
        cw(&w[0],  U0, ta, sA, mA);                                            \
        cw(&w[4],  U1, tb, sA, mA);                                            \
        cw(&w[8],  U2, tc, sA, mA);                                            \
        cw(&w[12], U3, td, sA, mA);                                            \
        _Pragma("unroll")                                                      \
        for (int e = 0; e < 16; ++e) den += w[e];                              \
        short8 af0, af1;                                                       \
        _Pragma("unroll")                                                      \
        for (int e = 0; e < 8; ++e) {                                          \
            af0[e] = f2bn(w[e]);                                               \
            af1[e] = f2bn(w[8 + e]);                                           \
        }                                                                      \
        _Pragma("unroll")                                                      \
        for (int c = 0; c < 8; ++c) {                                          \
            short8 bf = *(const short8*)&bt[c * 16 + arow][jl + g * 8];        \
            acc[c] = __builtin_amdgcn_mfma_f32_16x16x32_bf16(af0, bf, acc[c], 0, 0, 0); \
        }                                                                      \
        _Pragma("unroll")                                                      \
        for (int c = 0; c < 8; ++c) {                                          \
            short8 bf = *(const short8*)&bt[c * 16 + arow][jl + 32 + g * 8];   \
            acc[c] = __builtin_amdgcn_mfma_f32_16x16x32_bf16(af1, bf, acc[c], 0, 0, 0); \
        }                                                                      \
        U0 = f0; U1 = f1; U2 = f2; U3 = f3;                                    \
    }

    #pragma unroll 1
    for (int jp = 0; jp < 8; jp += 2) {
        K3_ITER(jp,     aA0, aA1, aA2, aA3);
        K3_ITER(jp + 1, aB0, aB1, aB2, aB3);
    }
#undef K3_ITER

    // den: sum the 4 g-copies per row
    den += __shfl_xor(den, 16, 64);
    den += __shfl_xor(den, 32, 64);
    if (g == 0) atomicAdd(&den_out[grow], den);

    // num partials
    const int orow0 = i0 + wave * 16;
    if (slice_mode) {
        unsigned short* dst = num_bf + (size_t)jc * ((size_t)N * FOUT);
        #pragma unroll
        for (int c = 0; c < 8; ++c)
            #pragma unroll
            for (int q = 0; q < 4; ++q)
                dst[(size_t)(orow0 + g * 4 + q) * FOUT + c * 16 + arow] = f2b(acc[c][q]);
    } else {
        #pragma unroll
        for (int c = 0; c < 8; ++c)
            #pragma unroll
            for (int q = 0; q < 4; ++q)
                atomicAdd(&num_f32[(size_t)(orow0 + g * 4 + q) * FOUT + c * 16 + arow], acc[c][q]);
    }
}

// Kernel 4: reduce j-chunk partials, normalize, project, logmap0, elu + a*cos.
__global__ __launch_bounds__(256) void k4_epi(
    const unsigned short* __restrict__ numb, const float* __restrict__ numf,
    const float* __restrict__ den, float* __restrict__ out, int bfmode)
{
    const int row = blockIdx.x * 16 + (threadIdx.x >> 4);
    const int col0 = (threadIdx.x & 15) * 8;
    const float inv = 1.0f / den[row];
    float v[8] = {};
    if (bfmode) {
        #pragma unroll 1
        for (int s5 = 0; s5 < NJC; ++s5) {
            short8 b = *(const short8*)(numb + (size_t)s5 * N * FOUT + (size_t)row * FOUT + col0);
            #pragma unroll
            for (int c = 0; c < 8; ++c)
                v[c] += __uint_as_float(((unsigned)(unsigned short)b[c]) << 16);
        }
    } else {
        #pragma unroll
        for (int c = 0; c < 8; ++c) v[c] = numf[(size_t)row * FOUT + col0 + c];
    }
    float ss = 0.f;
    #pragma unroll
    for (int c = 0; c < 8; ++c) { v[c] *= inv; ss += v[c] * v[c]; }
    #pragma unroll
    for (int m = 1; m < 16; m <<= 1) ss += __shfl_xor(ss, m, 16);
    float nrm = sqrtf(ss);
    const float maxn = 1.0f - EPS_BALL;
    float scale1 = nrm > maxn ? maxn / nrm : 1.0f;
    float pn = fminf(nrm, maxn);
    float fac;
    if (pn < 1e-6f) fac = scale1;   // artanh(x)/x -> 1
    else fac = scale1 * (0.5f * __logf((1.f + pn) / (1.f - pn))) / pn;
    float o[8];
    #pragma unroll
    for (int c = 0; c < 8; ++c) {
        float hv = v[c] * fac;
        float eluv = hv > 0.f ? hv : __expf(hv) - 1.f;
        o[c] = eluv + A_PARA * __cosf(hv + PHI);
    }
    float* op = out + (size_t)row * FOUT + col0;
    *(float4*)op = make_float4(o[0], o[1], o[2], o[3]);
    *(float4*)(op + 4) = make_float4(o[4], o[5], o[6], o[7]);
}

extern "C" void kernel_launch(void* const* d_in, const int* in_sizes, int n_in,
                              void* d_out, int out_size, void* d_ws, size_t ws_size,
                              hipStream_t stream) {
    const float* h   = (const float*)d_in[0];
    const int*   adj = (const int*)d_in[1];
    const float* W   = (const float*)d_in[2];
    const float* a   = (const float*)d_in[3];
    float* out = (float*)d_out;

    char* ws = (char*)d_ws;
    unsigned short* whbt = (unsigned short*)ws;                 // 2 MB bf16 Wh^T
    size_t off = (size_t)N * FOUT * 2;
    unsigned short* Wt = (unsigned short*)(ws + off); off += (size_t)FOUT * FIN * 2;  // 128 KB
    float* s  = (float*)(ws + off); off += (size_t)N * 4;
    float* tt = (float*)(ws + off); off += (size_t)N * 4;
    unsigned* Tkey = (unsigned*)(ws + off); off += 256;
    float* denb = (float*)(ws + off); off += (size_t)N * 4;
    const size_t slice_bytes = (size_t)N * FOUT * 2;            // bf16 slices, 2 MB each
    const bool fast = ws_size >= off + (size_t)NJC * slice_bytes;
    unsigned short* numb = fast ? (unsigned short*)(ws + off) : nullptr;

    if (!fast) hipMemsetAsync(out, 0, (size_t)N * FOUT * 4, stream);

    k0_wt<<<64, 256, 0, stream>>>(W, Wt, Tkey, denb);
    k1_gemm<<<N / 32, 256, 0, stream>>>(h, Wt, a, whbt, s, tt, Tkey);
    k3_attn<<<(N / 128) * NJC, 512, 0, stream>>>(adj, whbt, s, tt, Tkey, numb, out, denb, fast ? 1 : 0);
    k4_epi<<<N / 16, 256, 0, stream>>>(numb, out, denb, out, fast ? 1 : 0);
}

// Round 12
// 93.832 us; speedup vs baseline: 1.3011x; 1.3011x over previous
//
#include <hip/hip_runtime.h>
#include <hip/hip_bf16.h>
#include <math.h>

typedef short short8 __attribute__((ext_vector_type(8)));
typedef float f32x4 __attribute__((ext_vector_type(4)));

static constexpr int N = 8192;
static constexpr int FIN = 512;
static constexpr int FOUT = 128;
static constexpr int NJC = 8;       // j-chunks (BJ = N/NJC = 1024) — round-6/9 proven
static constexpr float PHI = 3.1415926f * 0.3f;
static constexpr float A_PARA = 0.5f;
static constexpr float EPS_BALL = 4e-3f;
static constexpr float L2E = 1.4426950408889634f;   // log2(e)

__device__ __forceinline__ unsigned short f2b(float f) {
    union { float f; unsigned u; } v; v.f = f;
    unsigned r = v.u + 0x7fffu + ((v.u >> 16) & 1u);
    return (unsigned short)(r >> 16);
}

// RN bf16 via HIP intrinsic (compiler can pair into v_cvt_pk_bf16_f32)
__device__ __forceinline__ short f2bn(float f) {
    __hip_bfloat16 h = __float2bfloat16(f);
    return *reinterpret_cast<short*>(&h);
}

// monotone f32 -> u32 key for atomicMax-based float max
__device__ __forceinline__ unsigned f2key(float x) {
    unsigned b = __float_as_uint(x);
    return (b & 0x80000000u) ? ~b : (b | 0x80000000u);
}
__device__ __forceinline__ float key2f(unsigned k) {
    unsigned b = (k & 0x80000000u) ? (k ^ 0x80000000u) : ~k;
    return __uint_as_float(b);
}

__device__ __forceinline__ short8 cvt8(float4 x0, float4 x1) {
    short8 r;
    r[0] = (short)f2b(x0.x); r[1] = (short)f2b(x0.y);
    r[2] = (short)f2b(x0.z); r[3] = (short)f2b(x0.w);
    r[4] = (short)f2b(x1.x); r[5] = (short)f2b(x1.y);
    r[6] = (short)f2b(x1.z); r[7] = (short)f2b(x1.w);
    return r;
}

// w = exp2( lrelu(s'+t') - m' ) masked by adj; everything pre-scaled by log2e.
__device__ __forceinline__ void cw(float* w, const int4 a, const float4 tv,
                                   float sA, float mA) {
    float z;
    z = sA + tv.x; w[0] = a.x > 0 ? __builtin_amdgcn_exp2f(fmaxf(z, 0.2f * z) - mA) : 0.f;
    z = sA + tv.y; w[1] = a.y > 0 ? __builtin_amdgcn_exp2f(fmaxf(z, 0.2f * z) - mA) : 0.f;
    z = sA + tv.z; w[2] = a.z > 0 ? __builtin_amdgcn_exp2f(fmaxf(z, 0.2f * z) - mA) : 0.f;
    z = sA + tv.w; w[3] = a.w > 0 ? __builtin_amdgcn_exp2f(fmaxf(z, 0.2f * z) - mA) : 0.f;
}

// Kernel 0: W f32[512][128] -> Wt bf16[128][512]; block 0 also zeroes Tkey + denb.
__global__ __launch_bounds__(256) void k0_wt(const float* __restrict__ W,
                                             unsigned short* __restrict__ Wt,
                                             unsigned* __restrict__ Tkey,
                                             float* __restrict__ denb) {
    __shared__ float sh[32][33];
    const int t = threadIdx.x;
    const int k0 = (blockIdx.x >> 2) * 32, c0 = (blockIdx.x & 3) * 32;
    {
        int r = t >> 3, c4 = (t & 7) * 4;
        float4 v = *(const float4*)(W + (size_t)(k0 + r) * FOUT + c0 + c4);
        sh[r][c4] = v.x; sh[r][c4 + 1] = v.y; sh[r][c4 + 2] = v.z; sh[r][c4 + 3] = v.w;
    }
    __syncthreads();
    int cc = t >> 3, k4 = (t & 7) * 4;
    ushort4 o;
    o.x = f2b(sh[k4][cc]); o.y = f2b(sh[k4 + 1][cc]);
    o.z = f2b(sh[k4 + 2][cc]); o.w = f2b(sh[k4 + 3][cc]);
    *(ushort4*)(Wt + (size_t)(c0 + cc) * FIN + k0 + k4) = o;
    if (blockIdx.x == 0) {
        if (t == 0) Tkey[0] = 0u;
        for (int i = t; i < N; i += 256) denb[i] = 0.f;
    }
}

// Kernel 1 (round-9 proven): Wh = h @ W via bf16 MFMA, full Wt staged in LDS.
__global__ __launch_bounds__(256) void k1_gemm(
    const float* __restrict__ h, const unsigned short* __restrict__ Wt,
    const float* __restrict__ a, unsigned short* __restrict__ whbt,
    float* __restrict__ s_out, float* __restrict__ t_out,
    unsigned* __restrict__ Tkey)
{
    __shared__ unsigned short wlds[128][520];   // 133 KB
    __shared__ unsigned short hsb[2][32][72];
    __shared__ float sred[32][2], tred[32][2];
    const int t = threadIdx.x, lane = t & 63, wave = t >> 6;
    const int i0 = blockIdx.x * 32;
    const int wr = wave & 1, wc = wave >> 1;
    const int arow = lane & 15, g = lane >> 4;
    const int sr = t >> 3, sc = (t & 7) * 8;
    const float* hp = h + (size_t)(i0 + sr) * FIN + sc;

    for (int idx = t; idx < (FOUT * FIN) / 8; idx += 256) {
        const int row = idx >> 6, col = (idx & 63) * 8;
        *(short8*)&wlds[row][col] = *(const short8*)(Wt + (size_t)row * FIN + col);
    }
    float4 x0 = *(const float4*)hp, x1 = *(const float4*)(hp + 4);
    *(short8*)&hsb[0][sr][sc] = cvt8(x0, x1);
    __syncthreads();

    f32x4 acc[4];
    const f32x4 zz = {0.f, 0.f, 0.f, 0.f};
    #pragma unroll
    for (int cf = 0; cf < 4; ++cf) acc[cf] = zz;

    #pragma unroll 1
    for (int kt = 0; kt < 8; ++kt) {
        const int cur = kt & 1;
        float4 y0, y1;
        if (kt < 7) {
            y0 = *(const float4*)(hp + (kt + 1) * 64);
            y1 = *(const float4*)(hp + (kt + 1) * 64 + 4);
        }
        #pragma unroll
        for (int js = 0; js < 64; js += 32) {
            short8 af = *(const short8*)&hsb[cur][wr * 16 + arow][js + g * 8];
            #pragma unroll
            for (int cf = 0; cf < 4; ++cf) {
                short8 bf = *(const short8*)&wlds[wc * 64 + cf * 16 + arow][kt * 64 + js + g * 8];
                acc[cf] = __builtin_amdgcn_mfma_f32_16x16x32_bf16(af, bf, acc[cf], 0, 0, 0);
            }
        }
        if (kt < 7) {
            *(short8*)&hsb[cur ^ 1][sr][sc] = cvt8(y0, y1);
            __syncthreads();
        }
    }

    float a1v[4], a2v[4];
    #pragma unroll
    for (int cf = 0; cf < 4; ++cf) {
        int col = wc * 64 + cf * 16 + arow;
        a1v[cf] = a[col]; a2v[cf] = a[FOUT + col];
    }
    #pragma unroll
    for (int cf = 0; cf < 4; ++cf) {
        int col = wc * 64 + cf * 16 + arow;
        ushort4 o;
        o.x = f2b(acc[cf][0]); o.y = f2b(acc[cf][1]);
        o.z = f2b(acc[cf][2]); o.w = f2b(acc[cf][3]);
        *(ushort4*)(whbt + (size_t)col * N + i0 + wr * 16 + g * 4) = o;
    }
    #pragma unroll
    for (int q = 0; q < 4; ++q) {
        float sp = acc[0][q]*a1v[0] + acc[1][q]*a1v[1] + acc[2][q]*a1v[2] + acc[3][q]*a1v[3];
        float tp = acc[0][q]*a2v[0] + acc[1][q]*a2v[1] + acc[2][q]*a2v[2] + acc[3][q]*a2v[3];
        #pragma unroll
        for (int m = 1; m < 16; m <<= 1) {
            sp += __shfl_xor(sp, m, 16);
            tp += __shfl_xor(tp, m, 16);
        }
        if (arow == 0) {
            sred[wr * 16 + g * 4 + q][wc] = sp;
            tred[wr * 16 + g * 4 + q][wc] = tp;
        }
    }
    __syncthreads();
    if (t < 32) {
        float sp = (sred[t][0] + sred[t][1]) * L2E;
        float tp = (tred[t][0] + tred[t][1]) * L2E;
        s_out[i0 + t] = sp;
        t_out[i0 + t] = tp;
        float m = tp;
        #pragma unroll
        for (int d = 1; d < 32; d <<= 1) m = fmaxf(m, __shfl_xor(m, d, 32));
        if (t == 0) atomicMax(Tkey, f2key(m));
    }
}

// Kernel 3 (round-9 proven): fused masked-softmax attention + PV (bf16 MFMA).
// BM=128, BJ=1024, grid 512, 2 blocks/CU. whbt tile prefetch 2-deep; adj 1-deep
// issued last (counted vmcnt; loads ride through the barrier).
__global__ __launch_bounds__(512, 4) void k3_attn(
    const int* __restrict__ adj, const unsigned short* __restrict__ whbt,
    const float* __restrict__ s_in, const float* __restrict__ t_in,
    const unsigned* __restrict__ Tkey,
    unsigned short* __restrict__ num_bf, float* __restrict__ num_f32,
    float* __restrict__ den_out, int slice_mode)
{
    __shared__ unsigned short bt[2][128][72];
    __shared__ float tl[1024];
    const int t = threadIdx.x, lane = t & 63, wave = t >> 6;
    const int jc = blockIdx.x & (NJC - 1), it = blockIdx.x / NJC;
    const int i0 = it * 128, jbase = jc * (N / NJC);

    tl[t] = t_in[jbase + t];
    tl[t + 512] = t_in[jbase + t + 512];

    const int arow = lane & 15, g = lane >> 4;
    const int grow = i0 + wave * 16 + arow;
    const float sA = s_in[grow];
    const float Tv = key2f(Tkey[0]);
    const float zT = sA + Tv;
    const float mA = fmaxf(zT, 0.2f * zT);
    const int* adjrow = adj + (size_t)grow * N;
    const int srow = t >> 2, scol = (t & 3) * 16;
    const unsigned short* sbase = whbt + (size_t)srow * N + jbase + scol;

    f32x4 acc[8];
    const f32x4 zz = {0.f, 0.f, 0.f, 0.f};
    #pragma unroll
    for (int c = 0; c < 8; ++c) acc[c] = zz;
    float den = 0.f;

    // prologue: stage bt tile 0 directly; prefetch whbt tile 1 (nc) + adj tile 0
    short8 s00 = *(const short8*)sbase;
    short8 s01 = *(const short8*)(sbase + 8);
    short8 nc0 = *(const short8*)(sbase + 64);
    short8 nc1 = *(const short8*)(sbase + 72);
    int4 av0 = *(const int4*)(adjrow + jbase + g * 8);
    int4 av1 = *(const int4*)(adjrow + jbase + g * 8 + 4);
    int4 av2 = *(const int4*)(adjrow + jbase + 32 + g * 8);
    int4 av3 = *(const int4*)(adjrow + jbase + 32 + g * 8 + 4);
    *(short8*)&bt[0][srow][scol]     = s00;
    *(short8*)&bt[0][srow][scol + 8] = s01;
    __syncthreads();

    #pragma unroll 1
    for (int jt = 0; jt < 16; ++jt) {
        const int cur = jt & 1, jl = jt * 64;
        // whbt tile jt+2 FIRST (consumed by the ds_write NEXT iter)
        const int jt2 = (jt + 2 < 16) ? jt + 2 : 15;
        short8 nn0, nn1;
        {
            const unsigned short* p = sbase + jt2 * 64;
            nn0 = *(const short8*)p;
            nn1 = *(const short8*)(p + 8);
        }
        // adj tile jt+1 LAST (stays in flight across the barrier)
        const int jt1 = (jt + 1 < 16) ? jt + 1 : 15;
        int4 an0, an1, an2, an3;
        {
            const int* ap = adjrow + jbase + jt1 * 64;
            an0 = *(const int4*)(ap + g * 8);
            an1 = *(const int4*)(ap + g * 8 + 4);
            an2 = *(const int4*)(ap + 32 + g * 8);
            an3 = *(const int4*)(ap + 32 + g * 8 + 4);
        }
        // t' from LDS (lgkm only)
        float4 ta = *(const float4*)&tl[jl + g * 8];
        float4 tb = *(const float4*)&tl[jl + g * 8 + 4];
        float4 tc = *(const float4*)&tl[jl + 32 + g * 8];
        float4 td = *(const float4*)&tl[jl + 32 + g * 8 + 4];
        // phase A: 16 w's straight into A-fragments (adj already in regs)
        float w[16];
        cw(&w[0],  av0, ta, sA, mA);
        cw(&w[4],  av1, tb, sA, mA);
        cw(&w[8],  av2, tc, sA, mA);
        cw(&w[12], av3, td, sA, mA);
        #pragma unroll
        for (int e = 0; e < 16; ++e) den += w[e];
        short8 af0, af1;
        #pragma unroll
        for (int e = 0; e < 8; ++e) {
            af0[e] = f2bn(w[e]);
            af1[e] = f2bn(w[8 + e]);
        }
        // phase B: 16 MFMA, B from LDS
        #pragma unroll
        for (int c = 0; c < 8; ++c) {
            short8 bf = *(const short8*)&bt[cur][c * 16 + arow][g * 8];
            acc[c] = __builtin_amdgcn_mfma_f32_16x16x32_bf16(af0, bf, acc[c], 0, 0, 0);
        }
        #pragma unroll
        for (int c = 0; c < 8; ++c) {
            short8 bf = *(const short8*)&bt[cur][c * 16 + arow][32 + g * 8];
            acc[c] = __builtin_amdgcn_mfma_f32_16x16x32_bf16(af1, bf, acc[c], 0, 0, 0);
        }
        // stage tile jt+1 from nc (loaded a full iter ago); shift pipelines
        if (jt < 15) {
            *(short8*)&bt[cur ^ 1][srow][scol]     = nc0;
            *(short8*)&bt[cur ^ 1][srow][scol + 8] = nc1;
            nc0 = nn0; nc1 = nn1;
            av0 = an0; av1 = an1; av2 = an2; av3 = an3;
            __syncthreads();
        }
    }

    // den: sum the 4 g-copies per row
    den += __shfl_xor(den, 16, 64);
    den += __shfl_xor(den, 32, 64);
    if (g == 0) atomicAdd(&den_out[grow], den);

    // num partials
    const int orow0 = i0 + wave * 16;
    if (slice_mode) {
        unsigned short* dst = num_bf + (size_t)jc * ((size_t)N * FOUT);
        #pragma unroll
        for (int c = 0; c < 8; ++c)
            #pragma unroll
            for (int q = 0; q < 4; ++q)
                dst[(size_t)(orow0 + g * 4 + q) * FOUT + c * 16 + arow] = f2b(acc[c][q]);
    } else {
        #pragma unroll
        for (int c = 0; c < 8; ++c)
            #pragma unroll
            for (int q = 0; q < 4; ++q)
                atomicAdd(&num_f32[(size_t)(orow0 + g * 4 + q) * FOUT + c * 16 + arow], acc[c][q]);
    }
}

// Kernel 4: reduce j-chunk partials, normalize, project, logmap0, elu + a*cos.
// Thread owns 8 CONTIGUOUS cols of one row -> short8 slice loads, float4 stores.
__global__ __launch_bounds__(256) void k4_epi(
    const unsigned short* __restrict__ numb, const float* __restrict__ numf,
    const float* __restrict__ den, float* __restrict__ out, int bfmode)
{
    const int row = blockIdx.x * 16 + (threadIdx.x >> 4);
    const int col0 = (threadIdx.x & 15) * 8;
    const float inv = 1.0f / den[row];
    float v[8] = {};
    if (bfmode) {
        #pragma unroll 1
        for (int s5 = 0; s5 < NJC; ++s5) {
            short8 b = *(const short8*)(numb + (size_t)s5 * N * FOUT + (size_t)row * FOUT + col0);
            #pragma unroll
            for (int c = 0; c < 8; ++c)
                v[c] += __uint_as_float(((unsigned)(unsigned short)b[c]) << 16);
        }
    } else {
        #pragma unroll
        for (int c = 0; c < 8; ++c) v[c] = numf[(size_t)row * FOUT + col0 + c];
    }
    float ss = 0.f;
    #pragma unroll
    for (int c = 0; c < 8; ++c) { v[c] *= inv; ss += v[c] * v[c]; }
    #pragma unroll
    for (int m = 1; m < 16; m <<= 1) ss += __shfl_xor(ss, m, 16);
    float nrm = sqrtf(ss);
    const float maxn = 1.0f - EPS_BALL;
    float scale1 = nrm > maxn ? maxn / nrm : 1.0f;
    float pn = fminf(nrm, maxn);
    float fac;
    if (pn < 1e-6f) fac = scale1;   // artanh(x)/x -> 1
    else fac = scale1 * (0.5f * __logf((1.f + pn) / (1.f - pn))) / pn;
    float o[8];
    #pragma unroll
    for (int c = 0; c < 8; ++c) {
        float hv = v[c] * fac;
        float eluv = hv > 0.f ? hv : __expf(hv) - 1.f;
        o[c] = eluv + A_PARA * __cosf(hv + PHI);
    }
    float* op = out + (size_t)row * FOUT + col0;
    *(float4*)op = make_float4(o[0], o[1], o[2], o[3]);
    *(float4*)(op + 4) = make_float4(o[4], o[5], o[6], o[7]);
}

extern "C" void kernel_launch(void* const* d_in, const int* in_sizes, int n_in,
                              void* d_out, int out_size, void* d_ws, size_t ws_size,
                              hipStream_t stream) {
    const float* h   = (const float*)d_in[0];
    const int*   adj = (const int*)d_in[1];
    const float* W   = (const float*)d_in[2];
    const float* a   = (const float*)d_in[3];
    float* out = (float*)d_out;

    char* ws = (char*)d_ws;
    unsigned short* whbt = (unsigned short*)ws;                 // 2 MB bf16 Wh^T
    size_t off = (size_t)N * FOUT * 2;
    unsigned short* Wt = (unsigned short*)(ws + off); off += (size_t)FOUT * FIN * 2;  // 128 KB
    float* s  = (float*)(ws + off); off += (size_t)N * 4;
    float* tt = (float*)(ws + off); off += (size_t)N * 4;
    unsigned* Tkey = (unsigned*)(ws + off); off += 256;
    float* denb = (float*)(ws + off); off += (size_t)N * 4;
    const size_t slice_bytes = (size_t)N * FOUT * 2;            // bf16 slices, 2 MB each
    const bool fast = ws_size >= off + (size_t)NJC * slice_bytes;
    unsigned short* numb = fast ? (unsigned short*)(ws + off) : nullptr;

    if (!fast) hipMemsetAsync(out, 0, (size_t)N * FOUT * 4, stream);

    k0_wt<<<64, 256, 0, stream>>>(W, Wt, Tkey, denb);
    k1_gemm<<<N / 32, 256, 0, stream>>>(h, Wt, a, whbt, s, tt, Tkey);
    k3_attn<<<(N / 128) * NJC, 512, 0, stream>>>(adj, whbt, s, tt, Tkey, numb, out, denb, fast ? 1 : 0);
    k4_epi<<<N / 16, 256, 0, stream>>>(numb, out, denb, out, fast ? 1 : 0);
}